// Round 1
// baseline (3916.388 us; speedup 1.0000x reference)
//
#include <hip/hip_runtime.h>
#include <math.h>

// ---------------- problem constants ----------------
#define B_    8
#define H_    56
#define W_    56
#define HW_   3136      // 56*56
#define C0_   256
#define C1_   512
#define C2_   1024
#define H1_   28
#define H2_   14
#define DIN_  1794      // 256+512+1024+2 coord channels
#define DOUT_ 448
#define NC_   3136      // number of centers

// ---------------- avg_pool2d(3,1,1) count_include_pad=True ----------------
__global__ void pool3_kernel(const float* __restrict__ in, float* __restrict__ out,
                             int nplane, int S) {
  int idx = blockIdx.x * blockDim.x + threadIdx.x;
  int total = nplane * S * S;
  if (idx >= total) return;
  int x = idx % S;
  int y = (idx / S) % S;
  int pl = idx / (S * S);
  const float* p = in + (size_t)pl * S * S;
  int y0 = max(y - 1, 0), y1 = min(y + 1, S - 1);
  int x0 = max(x - 1, 0), x1 = min(x + 1, S - 1);
  float s = 0.f;
  for (int yy = y0; yy <= y1; ++yy)
    for (int xx = x0; xx <= x1; ++xx)
      s += p[yy * S + xx];
  out[idx] = s * (1.0f / 9.0f);
}

// ---------------- |c_j|^2 over the center bank ----------------
__global__ void cent2_kernel(const float* __restrict__ C, float* __restrict__ c2) {
  int j = blockIdx.x * blockDim.x + threadIdx.x;
  if (j >= NC_) return;
  float s = 0.f;
  for (int d = 0; d < DOUT_; ++d) { float v = C[(size_t)d * NC_ + j]; s = fmaf(v, v, s); }
  c2[j] = s;
}

// ---------------- phi = 1x1 CoordConv over [pool0 | up(pool1) | up(pool2) | xx | yy] ----
// 8 pixels per block staged into LDS; lanes own OUTPUT channels (2 each):
// weight reads stream per-lane rows (L1 line reuse), sample reads are LDS broadcasts,
// no cross-lane reductions, phi stores coalesced.
#define SROW 1796   // 1794 padded to 16B multiple for float4 LDS reads
__global__ __launch_bounds__(256) void phi_kernel(
    const float* __restrict__ q0, const float* __restrict__ q1, const float* __restrict__ q2,
    const float* __restrict__ cw, const float* __restrict__ cb, float* __restrict__ phi) {
  __shared__ float s[8 * SROW];
  const int bpix0 = blockIdx.x * 8;

  // ---- stage sample descriptor for 8 pixels ----
  for (int t = threadIdx.x; t < 8 * DIN_; t += 256) {
    int p = t / DIN_;
    int d = t - p * DIN_;
    int pid = bpix0 + p;
    int b  = pid / HW_;
    int hw = pid - b * HW_;
    int h = hw / W_;
    int w = hw - h * W_;
    float v;
    if (d < C0_) {
      v = q0[(((size_t)b * C0_ + d) * H_ + h) * W_ + w];
    } else if (d < 1792) {
      int S; float r; const float* src;
      if (d < C0_ + C1_) { S = H1_; r = 0.5f;  src = q1 + ((size_t)b * C1_ + (d - C0_)) * (H1_ * H1_); }
      else               { S = H2_; r = 0.25f; src = q2 + ((size_t)b * C2_ + (d - C0_ - C1_)) * (H2_ * H2_); }
      // half-pixel bilinear (align_corners=False); edge clamp == jax renormalized triangle
      float sy = (h + 0.5f) * r - 0.5f;
      float sx = (w + 0.5f) * r - 0.5f;
      float fyf = floorf(sy), fxf = floorf(sx);
      float fy = sy - fyf, fx = sx - fxf;
      int iy = (int)fyf, ix = (int)fxf;
      int y0 = min(max(iy, 0), S - 1), y1 = min(max(iy + 1, 0), S - 1);
      int x0 = min(max(ix, 0), S - 1), x1 = min(max(ix + 1, 0), S - 1);
      float v00 = src[y0 * S + x0], v01 = src[y0 * S + x1];
      float v10 = src[y1 * S + x0], v11 = src[y1 * S + x1];
      float top = v00 + fx * (v01 - v00);
      float bot = v10 + fx * (v11 - v10);
      v = top + fy * (bot - top);
    } else if (d == 1792) {
      v = (float)h * (2.0f / 55.0f) - 1.0f;   // xx: varies along rows
    } else {
      v = (float)w * (2.0f / 55.0f) - 1.0f;   // yy: varies along cols
    }
    s[p * SROW + d] = v;
  }
  __syncthreads();

  // ---- each thread: output channels (tid) and (tid+256), 8 pixels ----
  const int oa = threadIdx.x;
  const int ob = min(threadIdx.x + 256, DOUT_ - 1);  // clamped; store guarded
  const float* wa = cw + (size_t)oa * DIN_;
  const float* wb = cw + (size_t)ob * DIN_;
  float acc[2][8];
#pragma unroll
  for (int q = 0; q < 2; ++q)
#pragma unroll
    for (int p = 0; p < 8; ++p) acc[q][p] = 0.f;

  for (int dc = 0; dc < 1792; dc += 4) {
    float4 sv[8];
#pragma unroll
    for (int p = 0; p < 8; ++p) sv[p] = *(const float4*)(s + p * SROW + dc);
    float2 a01 = *(const float2*)(wa + dc);
    float2 a23 = *(const float2*)(wa + dc + 2);
    float2 b01 = *(const float2*)(wb + dc);
    float2 b23 = *(const float2*)(wb + dc + 2);
#pragma unroll
    for (int p = 0; p < 8; ++p) {
      acc[0][p] = fmaf(a01.x, sv[p].x, acc[0][p]);
      acc[0][p] = fmaf(a01.y, sv[p].y, acc[0][p]);
      acc[0][p] = fmaf(a23.x, sv[p].z, acc[0][p]);
      acc[0][p] = fmaf(a23.y, sv[p].w, acc[0][p]);
      acc[1][p] = fmaf(b01.x, sv[p].x, acc[1][p]);
      acc[1][p] = fmaf(b01.y, sv[p].y, acc[1][p]);
      acc[1][p] = fmaf(b23.x, sv[p].z, acc[1][p]);
      acc[1][p] = fmaf(b23.y, sv[p].w, acc[1][p]);
    }
  }
  // tail: coord channels d = 1792, 1793
#pragma unroll
  for (int dt = 1792; dt < DIN_; ++dt) {
    float wva = wa[dt], wvb = wb[dt];
#pragma unroll
    for (int p = 0; p < 8; ++p) {
      float sval = s[p * SROW + dt];
      acc[0][p] = fmaf(wva, sval, acc[0][p]);
      acc[1][p] = fmaf(wvb, sval, acc[1][p]);
    }
  }

  float biasa = cb[oa];
  float biasb = cb[ob];
#pragma unroll
  for (int p = 0; p < 8; ++p) {
    int pid = bpix0 + p;
    phi[(size_t)pid * DOUT_ + oa] = acc[0][p] + biasa;
    if (threadIdx.x < DOUT_ - 256)
      phi[(size_t)pid * DOUT_ + threadIdx.x + 256] = acc[1][p] + biasb;
  }
}

// ---------------- streaming distance + top-3 + softmin score ----------------
__device__ __forceinline__ void insert3(float& t0, float& t1, float& t2, float v) {
  if (v < t2) {
    if (v < t1) {
      t2 = t1;
      if (v < t0) { t1 = t0; t0 = v; } else t1 = v;
    } else t2 = v;
  }
}
// merge two sorted ascending triples -> smallest three of the union
__device__ __forceinline__ void merge3(float& a0, float& a1, float& a2,
                                       float b0, float b1, float b2) {
  float lo0 = fminf(a0, b0), hi0 = fmaxf(a0, b0);
  float lo1 = fminf(a1, b1), hi1 = fmaxf(a1, b1);
  float lo2 = fminf(a2, b2);
  a0 = lo0;
  a1 = fminf(hi0, lo1);
  a2 = fminf(fmaxf(hi0, lo1), fminf(hi1, lo2));
}

__global__ __launch_bounds__(256) void dist_kernel(
    const float* __restrict__ phi, const float* __restrict__ C,
    const float* __restrict__ c2g, float* __restrict__ out) {
  __shared__ float phT[DOUT_ * 16];   // [d][row] transposed, 28.7 KB
  const int row0 = blockIdx.x * 16;
  for (int i = threadIdx.x; i < DOUT_ * 16; i += 256) {
    int d = i >> 4, r = i & 15;
    phT[i] = phi[(size_t)(row0 + r) * DOUT_ + d];
  }
  __syncthreads();

  const int wave = threadIdx.x >> 6;   // 4 waves, each owns 4 rows
  const int lane = threadIdx.x & 63;

  // feat2 = |phi_row|^2 for this wave's rows (once per block, cost negligible)
  float f2[4];
#pragma unroll
  for (int k = 0; k < 4; ++k) {
    int r = wave * 4 + k;
    float sacc = 0.f;
    for (int d = lane; d < DOUT_; d += 64) { float v = phT[(d << 4) + r]; sacc = fmaf(v, v, sacc); }
#pragma unroll
    for (int m = 32; m; m >>= 1) sacc += __shfl_xor(sacc, m, 64);
    f2[k] = sacc;
  }

  float t3[4][3];
#pragma unroll
  for (int r = 0; r < 4; ++r) { t3[r][0] = 1e30f; t3[r][1] = 1e30f; t3[r][2] = 1e30f; }

  for (int jb = 0; jb < NC_; jb += 512) {
    int jA = jb + (lane << 2);
    int jB = jA + 256;
    int jAc = min(jA, NC_ - 4);   // clamp for safe loads; invalid j filtered below
    int jBc = min(jB, NC_ - 4);
    const float* CA = C + jAc;
    const float* CB = C + jBc;
    float acc[4][8];
#pragma unroll
    for (int r = 0; r < 4; ++r)
#pragma unroll
      for (int k = 0; k < 8; ++k) acc[r][k] = 0.f;

#pragma unroll 2
    for (int d = 0; d < DOUT_; ++d) {
      float4 a  = *(const float4*)(phT + (d << 4) + (wave << 2));  // broadcast
      float4 vA = *(const float4*)(CA + (size_t)d * NC_);          // coalesced 1KB/wave
      float4 vB = *(const float4*)(CB + (size_t)d * NC_);
#pragma unroll
      for (int r = 0; r < 4; ++r) {
        float av = (r == 0) ? a.x : (r == 1) ? a.y : (r == 2) ? a.z : a.w;
        acc[r][0] = fmaf(av, vA.x, acc[r][0]);
        acc[r][1] = fmaf(av, vA.y, acc[r][1]);
        acc[r][2] = fmaf(av, vA.z, acc[r][2]);
        acc[r][3] = fmaf(av, vA.w, acc[r][3]);
        acc[r][4] = fmaf(av, vB.x, acc[r][4]);
        acc[r][5] = fmaf(av, vB.y, acc[r][5]);
        acc[r][6] = fmaf(av, vB.z, acc[r][6]);
        acc[r][7] = fmaf(av, vB.w, acc[r][7]);
      }
    }

    float4 cA = *(const float4*)(c2g + jAc);
    float4 cB = *(const float4*)(c2g + jBc);
    float c2arr[8] = {cA.x, cA.y, cA.z, cA.w, cB.x, cB.y, cB.z, cB.w};
#pragma unroll
    for (int k = 0; k < 8; ++k) {
      int j = (k < 4) ? (jA + k) : (jB + k - 4);
      if (j < NC_) {
#pragma unroll
        for (int r = 0; r < 4; ++r) {
          float d2 = f2[r] + c2arr[k] - 2.0f * acc[r][k];
          float dist = sqrtf(fmaxf(d2, 0.f));
          insert3(t3[r][0], t3[r][1], t3[r][2], dist);
        }
      }
    }
  }

  // butterfly merge across the 64 lanes (all lanes hold candidates for same 4 rows)
#pragma unroll
  for (int m = 1; m < 64; m <<= 1) {
#pragma unroll
    for (int r = 0; r < 4; ++r) {
      float b0 = __shfl_xor(t3[r][0], m, 64);
      float b1 = __shfl_xor(t3[r][1], m, 64);
      float b2 = __shfl_xor(t3[r][2], m, 64);
      merge3(t3[r][0], t3[r][1], t3[r][2], b0, b1, b2);
    }
  }

  if (lane == 0) {
#pragma unroll
    for (int r = 0; r < 4; ++r) {
      float d0 = t3[r][0], d1 = t3[r][1], d2v = t3[r][2];
      // softmax(-[d0,d1,d2])[0] * d0, stable since d0 is the min
      float s0 = 1.0f / (1.0f + expf(d0 - d1) + expf(d0 - d2v));
      out[row0 + wave * 4 + r] = s0 * d0;
    }
  }
}

// ---------------- launch ----------------
extern "C" void kernel_launch(void* const* d_in, const int* in_sizes, int n_in,
                              void* d_out, int out_size, void* d_ws, size_t ws_size,
                              hipStream_t stream) {
  const float* p0 = (const float*)d_in[0];
  const float* p1 = (const float*)d_in[1];
  const float* p2 = (const float*)d_in[2];
  const float* cw = (const float*)d_in[3];
  const float* cb = (const float*)d_in[4];
  const float* C  = (const float*)d_in[5];
  float* out = (float*)d_out;

  // workspace layout (floats): pooled pyramids + phi + cent2  (~90 MB)
  float* ws  = (float*)d_ws;
  float* q0  = ws;                    // 8*256*56*56  = 6,422,528
  float* q1  = q0 + 6422528;          // 8*512*28*28  = 3,211,264
  float* q2  = q1 + 3211264;          // 8*1024*14*14 = 1,605,632
  float* phi = q2 + 1605632;          // 25088*448    = 11,239,424
  float* c2  = phi + 11239424;        // 3,136

  pool3_kernel<<<(6422528 + 255) / 256, 256, 0, stream>>>(p0, q0, 8 * C0_, 56);
  pool3_kernel<<<(3211264 + 255) / 256, 256, 0, stream>>>(p1, q1, 8 * C1_, 28);
  pool3_kernel<<<(1605632 + 255) / 256, 256, 0, stream>>>(p2, q2, 8 * C2_, 14);
  cent2_kernel<<<(NC_ + 255) / 256, 256, 0, stream>>>(C, c2);
  phi_kernel<<<3136, 256, 0, stream>>>(q0, q1, q2, cw, cb, phi);
  dist_kernel<<<25088 / 16, 256, 0, stream>>>(phi, C, c2, out);
}

// Round 2
// 1232.999 us; speedup vs baseline: 3.1763x; 3.1763x over previous
//
#include <hip/hip_runtime.h>
#include <math.h>

// ---------------- problem constants ----------------
#define B_    8
#define H_    56
#define W_    56
#define HW_   3136
#define C0_   256
#define C1_   512
#define C2_   1024
#define H1_   28
#define H2_   14
#define DIN_  1794      // 256+512+1024+2
#define KPAD_ 1824      // DIN_ padded to 57 chunks of 32
#define KCP_  57        // phi K-chunks
#define DOUT_ 448
#define NCHP_ 28        // phi N-chunks (448/16)
#define NC_   3136      // centers
#define NCHD_ 196       // dist N-chunks (3136/16)
#define KCD_  14        // dist K-chunks (448/32)
#define SROW_ 1832      // LDS desc row stride (shorts): 916 dwords, 916%8==4 -> 2-way only
#define DTS_  456       // LDS D-tile row stride (floats)

typedef __attribute__((ext_vector_type(8))) short bh8;
typedef __attribute__((ext_vector_type(4))) float f32x4;

__device__ __forceinline__ short f2bf(float f) {
  union { float f; unsigned u; } v; v.f = f;
  unsigned r = v.u + 0x7fffu + ((v.u >> 16) & 1u);
  return (short)(r >> 16);
}
__device__ __forceinline__ float bf2f(short s) {
  union { unsigned u; float f; } v; v.u = ((unsigned)(unsigned short)s) << 16;
  return v.f;
}

// ---------------- avg_pool2d(3,1,1) count_include_pad ----------------
__global__ void pool3_kernel(const float* __restrict__ in, float* __restrict__ out,
                             int nplane, int S) {
  int idx = blockIdx.x * blockDim.x + threadIdx.x;
  int total = nplane * S * S;
  if (idx >= total) return;
  int x = idx % S;
  int y = (idx / S) % S;
  int pl = idx / (S * S);
  const float* p = in + (size_t)pl * S * S;
  int y0 = max(y - 1, 0), y1 = min(y + 1, S - 1);
  int x0 = max(x - 1, 0), x1 = min(x + 1, S - 1);
  float s = 0.f;
  for (int yy = y0; yy <= y1; ++yy)
    for (int xx = x0; xx <= x1; ++xx)
      s += p[yy * S + xx];
  out[idx] = s * (1.0f / 9.0f);
}

// ---------------- |c_j|^2 from bf16-rounded C (consistency with MFMA dot) ----
__global__ void cent2_kernel(const float* __restrict__ C, float* __restrict__ c2) {
  int j = blockIdx.x * blockDim.x + threadIdx.x;
  if (j >= NC_) return;
  float s = 0.f;
  for (int d = 0; d < DOUT_; ++d) {
    float v = bf2f(f2bf(C[(size_t)d * NC_ + j]));
    s = fmaf(v, v, s);
  }
  c2[j] = s;
}

// ---------------- pack C (K=448 x N=3136) into B-frag layout ----------------
// Cpack[nc][kc][lane][8]: value = C[k = kc*32+(lane>>4)*8+j][n = nc*16+(lane&15)]
__global__ void cpack_kernel(const float* __restrict__ C, short* __restrict__ Cpk) {
  int idx = blockIdx.x * 256 + threadIdx.x;       // NCHD_*KCD_*64 = 175616 exact
  int ln = idx & 63;
  int kc = (idx >> 6) % KCD_;
  int nc = idx / (KCD_ * 64);
  int n  = nc * 16 + (ln & 15);
  int k0 = kc * 32 + ((ln >> 4) << 3);
  bh8 o;
#pragma unroll
  for (int j = 0; j < 8; ++j) o[j] = f2bf(C[(size_t)(k0 + j) * NC_ + n]);
  *(bh8*)(Cpk + (size_t)idx * 8) = o;
}

// ---------------- pack W^T (K=1824pad x N=448) into B-frag layout ----------------
__global__ void wpack_kernel(const float* __restrict__ W, short* __restrict__ Wpk) {
  int idx = blockIdx.x * 256 + threadIdx.x;       // NCHP_*KCP_*64 = 102144
  if (idx >= NCHP_ * KCP_ * 64) return;
  int ln = idx & 63;
  int kc = (idx >> 6) % KCP_;
  int nc = idx / (KCP_ * 64);
  int n  = nc * 16 + (ln & 15);
  int k0 = kc * 32 + ((ln >> 4) << 3);
  bh8 o;
#pragma unroll
  for (int j = 0; j < 8; ++j) {
    int k = k0 + j;
    o[j] = (k < DIN_) ? f2bf(W[(size_t)n * DIN_ + k]) : (short)0;
  }
  *(bh8*)(Wpk + (size_t)idx * 8) = o;
}

// ---------------- phi: descriptor tile in LDS -> MFMA vs Wpack -> phipack ----
__global__ __launch_bounds__(256) void phi_mfma(
    const float* __restrict__ q0, const float* __restrict__ q1, const float* __restrict__ q2,
    const short* __restrict__ Wpk, const float* __restrict__ cb, short* __restrict__ phip) {
  __shared__ __align__(16) short s[16 * SROW_];   // 58.6 KB; reused as fp32 D-tile later
  const int pix0 = blockIdx.x * 16;

  // ---- stage 16 x 1824 bf16 descriptor; 8-channel groups share bilinear weights ----
  for (int item = threadIdx.x; item < 16 * (KPAD_ / 8); item += 256) {
    int p  = item / (KPAD_ / 8);
    int kg = item - p * (KPAD_ / 8);
    int k0 = kg << 3;
    int pid = pix0 + p;
    int b  = pid / HW_;
    int hw = pid - b * HW_;
    int h = hw / W_, w = hw - (hw / W_) * W_;
    bh8 o;
    if (k0 < C0_) {
      const float* src = q0 + (((size_t)b * C0_ + k0) * H_ + h) * W_ + w;
#pragma unroll
      for (int j = 0; j < 8; ++j) o[j] = f2bf(src[(size_t)j * HW_]);
    } else if (k0 < 1792) {
      int S; float r; const float* src;
      if (k0 < C0_ + C1_) { S = H1_; r = 0.5f;  src = q1 + ((size_t)b * C1_ + (k0 - C0_)) * (H1_ * H1_); }
      else                { S = H2_; r = 0.25f; src = q2 + ((size_t)b * C2_ + (k0 - C0_ - C1_)) * (H2_ * H2_); }
      float sy = (h + 0.5f) * r - 0.5f;
      float sx = (w + 0.5f) * r - 0.5f;
      float fyf = floorf(sy), fxf = floorf(sx);
      float fy = sy - fyf, fx = sx - fxf;
      int iy = (int)fyf, ix = (int)fxf;
      int y0 = min(max(iy, 0), S - 1), y1 = min(max(iy + 1, 0), S - 1);
      int x0 = min(max(ix, 0), S - 1), x1 = min(max(ix + 1, 0), S - 1);
      int o00 = y0 * S + x0, o01 = y0 * S + x1, o10 = y1 * S + x0, o11 = y1 * S + x1;
      int ss = S * S;
#pragma unroll
      for (int j = 0; j < 8; ++j) {
        float v00 = src[o00], v01 = src[o01], v10 = src[o10], v11 = src[o11];
        float top = v00 + fx * (v01 - v00);
        float bot = v10 + fx * (v11 - v10);
        o[j] = f2bf(top + fy * (bot - top));
        src += ss;
      }
    } else {
#pragma unroll
      for (int j = 0; j < 8; ++j) {
        int k = k0 + j;
        float v = (k == 1792) ? ((float)h * (2.0f / 55.0f) - 1.0f)
                : (k == 1793) ? ((float)w * (2.0f / 55.0f) - 1.0f) : 0.0f;
        o[j] = f2bf(v);
      }
    }
    *(bh8*)(s + p * SROW_ + k0) = o;
  }
  __syncthreads();

  // ---- MFMA: each wave owns 7 N-chunks; A-frag read once per K-chunk ----
  const int wv = threadIdx.x >> 6, ln = threadIdx.x & 63;
  f32x4 acc[7];
#pragma unroll
  for (int i = 0; i < 7; ++i) acc[i] = (f32x4){0.f, 0.f, 0.f, 0.f};
  const short* sA = s + (ln & 15) * SROW_ + ((ln >> 4) << 3);
  for (int kc = 0; kc < KCP_; ++kc) {
    bh8 a = *(const bh8*)(sA + kc * 32);
    const short* bp = Wpk + ((size_t)(wv * 7) * KCP_ + kc) * 512 + ln * 8;
#pragma unroll
    for (int i = 0; i < 7; ++i) {
      bh8 b = *(const bh8*)(bp + (size_t)i * KCP_ * 512);
      acc[i] = __builtin_amdgcn_mfma_f32_16x16x32_bf16(a, b, acc[i], 0, 0, 0);
    }
  }
  __syncthreads();

  // ---- epilogue: bias, stash fp32 tile in LDS (union over descriptor) ----
  float* Dt = (float*)s;
#pragma unroll
  for (int i = 0; i < 7; ++i) {
    int col = (wv * 7 + i) * 16 + (ln & 15);
    float bias = cb[col];
#pragma unroll
    for (int r = 0; r < 4; ++r) {
      int row = ((ln >> 4) << 2) + r;
      Dt[row * DTS_ + col] = acc[i][r] + bias;
    }
  }
  __syncthreads();

  // ---- repack to A-frag layout for the dist kernel ----
  for (int item = threadIdx.x; item < KCD_ * 64; item += 256) {
    int kc = item >> 6, lp = item & 63;
    int m = lp & 15, k0 = kc * 32 + ((lp >> 4) << 3);
    bh8 o;
#pragma unroll
    for (int j = 0; j < 8; ++j) o[j] = f2bf(Dt[m * DTS_ + k0 + j]);
    *(bh8*)(phip + (((size_t)blockIdx.x * KCD_ + kc) * 64 + lp) * 8) = o;
  }
}

// ---------------- dist: MFMA vs Cpack + streaming top-3 + softmin ----------------
__device__ __forceinline__ void insert3(float& t0, float& t1, float& t2, float v) {
  if (v < t2) {
    if (v < t1) {
      t2 = t1;
      if (v < t0) { t1 = t0; t0 = v; } else t1 = v;
    } else t2 = v;
  }
}
__device__ __forceinline__ void merge3(float& a0, float& a1, float& a2,
                                       float b0, float b1, float b2) {
  float lo0 = fminf(a0, b0), hi0 = fmaxf(a0, b0);
  float lo1 = fminf(a1, b1), hi1 = fmaxf(a1, b1);
  float lo2 = fminf(a2, b2);
  a0 = lo0;
  a1 = fminf(hi0, lo1);
  a2 = fminf(fmaxf(hi0, lo1), fminf(hi1, lo2));
}

__global__ __launch_bounds__(256) void dist_mfma(
    const short* __restrict__ phip, const short* __restrict__ Cpk,
    const float* __restrict__ c2g, float* __restrict__ out) {
  const int wv = threadIdx.x >> 6, ln = threadIdx.x & 63;

  // pin all 28 A-frags (32 pixels x 448 K) in registers
  bh8 A[2][KCD_];
#pragma unroll
  for (int rc = 0; rc < 2; ++rc) {
    const short* ap = phip + (((size_t)(blockIdx.x * 2 + rc) * KCD_) * 64 + ln) * 8;
#pragma unroll
    for (int kc = 0; kc < KCD_; ++kc) A[rc][kc] = *(const bh8*)(ap + (size_t)kc * 512);
  }

  // f2 per pixel row from the bf16 frags (self-consistent with the MFMA dot)
  float f2r[2][4];
#pragma unroll
  for (int rc = 0; rc < 2; ++rc) {
    float sum = 0.f;
#pragma unroll
    for (int kc = 0; kc < KCD_; ++kc)
#pragma unroll
      for (int j = 0; j < 8; ++j) { float v = bf2f(A[rc][kc][j]); sum = fmaf(v, v, sum); }
    sum += __shfl_xor(sum, 16, 64);
    sum += __shfl_xor(sum, 32, 64);   // all lanes: f2 of row (ln&15)
#pragma unroll
    for (int r = 0; r < 4; ++r) f2r[rc][r] = __shfl(sum, ((ln >> 4) << 2) + r, 64);
  }

  float t3[2][4][3];
#pragma unroll
  for (int rc = 0; rc < 2; ++rc)
#pragma unroll
    for (int r = 0; r < 4; ++r) { t3[rc][r][0] = 1e30f; t3[rc][r][1] = 1e30f; t3[rc][r][2] = 1e30f; }

  for (int i = 0; i < NCHD_ / 4; ++i) {
    int nc = i * 4 + wv;
    f32x4 acc0 = {0.f, 0.f, 0.f, 0.f}, acc1 = {0.f, 0.f, 0.f, 0.f};
    const short* bp = Cpk + (size_t)nc * KCD_ * 512 + ln * 8;
#pragma unroll
    for (int kc = 0; kc < KCD_; ++kc) {
      bh8 b = *(const bh8*)(bp + kc * 512);
      acc0 = __builtin_amdgcn_mfma_f32_16x16x32_bf16(A[0][kc], b, acc0, 0, 0, 0);
      acc1 = __builtin_amdgcn_mfma_f32_16x16x32_bf16(A[1][kc], b, acc1, 0, 0, 0);
    }
    float c2v = c2g[nc * 16 + (ln & 15)];
#pragma unroll
    for (int r = 0; r < 4; ++r) {
      insert3(t3[0][r][0], t3[0][r][1], t3[0][r][2], f2r[0][r] + c2v - 2.0f * acc0[r]);
      insert3(t3[1][r][0], t3[1][r][1], t3[1][r][2], f2r[1][r] + c2v - 2.0f * acc1[r]);
    }
  }

  // merge the 16 lanes that hold the same pixel row (cols differ)
#pragma unroll
  for (int m = 1; m <= 8; m <<= 1) {
#pragma unroll
    for (int rc = 0; rc < 2; ++rc)
#pragma unroll
      for (int r = 0; r < 4; ++r) {
        float b0 = __shfl_xor(t3[rc][r][0], m, 64);
        float b1 = __shfl_xor(t3[rc][r][1], m, 64);
        float b2 = __shfl_xor(t3[rc][r][2], m, 64);
        merge3(t3[rc][r][0], t3[rc][r][1], t3[rc][r][2], b0, b1, b2);
      }
  }

  __shared__ float mb[4][32][3];
  if ((ln & 15) == 0) {
#pragma unroll
    for (int rc = 0; rc < 2; ++rc)
#pragma unroll
      for (int r = 0; r < 4; ++r) {
        int row = rc * 16 + ((ln >> 4) << 2) + r;
        mb[wv][row][0] = t3[rc][r][0];
        mb[wv][row][1] = t3[rc][r][1];
        mb[wv][row][2] = t3[rc][r][2];
      }
  }
  __syncthreads();
  if (threadIdx.x < 32) {
    int row = threadIdx.x;
    float a0 = mb[0][row][0], a1 = mb[0][row][1], a2 = mb[0][row][2];
#pragma unroll
    for (int w2 = 1; w2 < 4; ++w2) merge3(a0, a1, a2, mb[w2][row][0], mb[w2][row][1], mb[w2][row][2]);
    float d0 = sqrtf(fmaxf(a0, 0.f));
    float d1 = sqrtf(fmaxf(a1, 0.f));
    float d2 = sqrtf(fmaxf(a2, 0.f));
    float s0 = 1.0f / (1.0f + expf(d0 - d1) + expf(d0 - d2));
    out[blockIdx.x * 32 + row] = s0 * d0;
  }
}

// ---------------- launch ----------------
extern "C" void kernel_launch(void* const* d_in, const int* in_sizes, int n_in,
                              void* d_out, int out_size, void* d_ws, size_t ws_size,
                              hipStream_t stream) {
  const float* p0 = (const float*)d_in[0];
  const float* p1 = (const float*)d_in[1];
  const float* p2 = (const float*)d_in[2];
  const float* cw = (const float*)d_in[3];
  const float* cb = (const float*)d_in[4];
  const float* C  = (const float*)d_in[5];
  float* out = (float*)d_out;

  // workspace layout (floats / shorts), ~73.5 MB total
  float* ws   = (float*)d_ws;
  float* q0   = ws;                         // 6,422,528 f
  float* q1   = q0 + 6422528;               // 3,211,264 f
  float* q2   = q1 + 3211264;               // 1,605,632 f
  float* c2   = q2 + 1605632;               //     3,136 f
  short* phip = (short*)(c2 + 3136);        // 11,239,424 s = 5,619,712 f
  short* Cpk  = phip + 11239424;            //  1,404,928 s =   702,464 f
  short* Wpk  = Cpk + 1404928;              //  1,634,304 s =   817,152 f

  pool3_kernel<<<(6422528 + 255) / 256, 256, 0, stream>>>(p0, q0, 8 * C0_, 56);
  pool3_kernel<<<(3211264 + 255) / 256, 256, 0, stream>>>(p1, q1, 8 * C1_, 28);
  pool3_kernel<<<(1605632 + 255) / 256, 256, 0, stream>>>(p2, q2, 8 * C2_, 14);
  cent2_kernel<<<(NC_ + 255) / 256, 256, 0, stream>>>(C, c2);
  cpack_kernel<<<NCHD_ * KCD_ * 64 / 256, 256, 0, stream>>>(C, Cpk);
  wpack_kernel<<<(NCHP_ * KCP_ * 64 + 255) / 256, 256, 0, stream>>>(cw, Wpk);
  phi_mfma<<<25088 / 16, 256, 0, stream>>>(q0, q1, q2, Wpk, cb, phip);
  dist_mfma<<<25088 / 32, 256, 0, stream>>>(phip, Cpk, c2, out);
}

// Round 3
// 849.779 us; speedup vs baseline: 4.6087x; 1.4510x over previous
//
#include <hip/hip_runtime.h>
#include <math.h>

// ---------------- problem constants ----------------
#define B_    8
#define H_    56
#define W_    56
#define HW_   3136
#define C0_   256
#define C1_   512
#define C2_   1024
#define DIN_  1794      // raw conv_w K (includes 2 coord cols, folded into epilogue)
#define KD_   1792      // descriptor K (GEMM K), 56 chunks of 32
#define KCP_  56        // phi K-chunks
#define DOUT_ 448
#define NCHP_ 28        // phi N-chunks (448/16)
#define NC_   3136      // centers
#define NCHD_ 196       // dist N-chunks (3136/16)
#define KCD_  14        // dist K-chunks (448/32)
#define DTS_  452       // LDS D-tile row stride (floats)
#define PCH_  28672     // phip chunk stride in shorts (= 16 pixels * 1792, in-place alias)

typedef __attribute__((ext_vector_type(8))) short bh8;
typedef __attribute__((ext_vector_type(4))) float f32x4;

__device__ __forceinline__ short f2bf(float f) {
  union { float f; unsigned u; } v; v.f = f;
  unsigned r = v.u + 0x7fffu + ((v.u >> 16) & 1u);
  return (short)(r >> 16);
}
__device__ __forceinline__ float bf2f(short s) {
  union { unsigned u; float f; } v; v.u = ((unsigned)(unsigned short)s) << 16;
  return v.f;
}

// ======== desc0: pool(p0) -> desc[:, 0:256], transposed, bf16 ========
// grid (4 chunks, 56 h, 8 b); coalesced reads along w; LDS vertical sums.
__global__ __launch_bounds__(256) void desc0_kernel(const float* __restrict__ p0,
                                                    short* __restrict__ desc) {
  __shared__ float sv[64 * 57];
  const int c0 = blockIdx.x * 64, h = blockIdx.y, b = blockIdx.z;
  for (int item = threadIdx.x; item < 64 * 56; item += 256) {
    int x = item % 56, c = item / 56;
    const float* src = p0 + (((size_t)(b * C0_ + c0 + c)) * 56 + h) * 56 + x;
    float s = src[0];
    if (h > 0)  s += src[-56];
    if (h < 55) s += src[56];
    sv[c * 57 + x] = s;
  }
  __syncthreads();
  for (int item = threadIdx.x; item < 56 * 8; item += 256) {
    int g = item & 7, w = item >> 3;
    bh8 o;
#pragma unroll
    for (int j = 0; j < 8; ++j) {
      const float* s0 = sv + (g * 8 + j) * 57;
      float v = s0[w];
      if (w > 0)  v += s0[w - 1];
      if (w < 55) v += s0[w + 1];
      o[j] = f2bf(v * (1.0f / 9.0f));
    }
    size_t pid = (size_t)b * HW_ + h * 56 + w;
    *(bh8*)(desc + pid * KD_ + c0 + g * 8) = o;
  }
}

// ======== desc1: pool(p1)+bilinear x2 -> desc[:, 256:768] ========
// grid (8 chunks, 56 h, 8 b)
__global__ __launch_bounds__(256) void desc1_kernel(const float* __restrict__ p1,
                                                    short* __restrict__ desc) {
  __shared__ float sv[2 * 64 * 29];
  const int c0 = blockIdx.x * 64, h = blockIdx.y, b = blockIdx.z;
  float sy = (h + 0.5f) * 0.5f - 0.5f;
  float fyf = floorf(sy);
  float fy = sy - fyf;
  int iy = (int)fyf;
  int pya = min(max(iy, 0), 27), pyb = min(max(iy + 1, 0), 27);
  for (int item = threadIdx.x; item < 64 * 2 * 28; item += 256) {
    int x = item % 28;
    int pr = (item / 28) & 1;
    int c = item / 56;
    int r = pr ? pyb : pya;
    const float* src = p1 + (((size_t)(b * C1_ + c0 + c)) * 28 + r) * 28 + x;
    float s = src[0];
    if (r > 0)  s += src[-28];
    if (r < 27) s += src[28];
    sv[pr * (64 * 29) + c * 29 + x] = s;
  }
  __syncthreads();
  for (int item = threadIdx.x; item < 56 * 8; item += 256) {
    int g = item & 7, w = item >> 3;
    float sx = (w + 0.5f) * 0.5f - 0.5f;
    float fxf = floorf(sx);
    float fx = sx - fxf;
    int ix = (int)fxf;
    int x0 = min(max(ix, 0), 27), x1 = min(max(ix + 1, 0), 27);
    bh8 o;
#pragma unroll
    for (int j = 0; j < 8; ++j) {
      const float* s0 = sv + (g * 8 + j) * 29;
      const float* s1 = s0 + 64 * 29;
      float p00 = s0[x0] + (x0 > 0 ? s0[x0 - 1] : 0.f) + (x0 < 27 ? s0[x0 + 1] : 0.f);
      float p01 = s0[x1] + (x1 > 0 ? s0[x1 - 1] : 0.f) + (x1 < 27 ? s0[x1 + 1] : 0.f);
      float p10 = s1[x0] + (x0 > 0 ? s1[x0 - 1] : 0.f) + (x0 < 27 ? s1[x0 + 1] : 0.f);
      float p11 = s1[x1] + (x1 > 0 ? s1[x1 - 1] : 0.f) + (x1 < 27 ? s1[x1 + 1] : 0.f);
      float top = p00 + fx * (p01 - p00);
      float bot = p10 + fx * (p11 - p10);
      o[j] = f2bf((top + fy * (bot - top)) * (1.0f / 9.0f));
    }
    size_t pid = (size_t)b * HW_ + h * 56 + w;
    *(bh8*)(desc + pid * KD_ + C0_ + c0 + g * 8) = o;
  }
}

// ======== desc2: pool(p2)+bilinear x4 -> desc[:, 768:1792] ========
// grid (16 chunks, 56 h, 8 b)
__global__ __launch_bounds__(256) void desc2_kernel(const float* __restrict__ p2,
                                                    short* __restrict__ desc) {
  __shared__ float sv[2 * 64 * 15];
  const int c0 = blockIdx.x * 64, h = blockIdx.y, b = blockIdx.z;
  float sy = (h + 0.5f) * 0.25f - 0.5f;
  float fyf = floorf(sy);
  float fy = sy - fyf;
  int iy = (int)fyf;
  int pya = min(max(iy, 0), 13), pyb = min(max(iy + 1, 0), 13);
  for (int item = threadIdx.x; item < 64 * 2 * 14; item += 256) {
    int x = item % 14;
    int pr = (item / 14) & 1;
    int c = item / 28;
    int r = pr ? pyb : pya;
    const float* src = p2 + (((size_t)(b * C2_ + c0 + c)) * 14 + r) * 14 + x;
    float s = src[0];
    if (r > 0)  s += src[-14];
    if (r < 13) s += src[14];
    sv[pr * (64 * 15) + c * 15 + x] = s;
  }
  __syncthreads();
  for (int item = threadIdx.x; item < 56 * 8; item += 256) {
    int g = item & 7, w = item >> 3;
    float sx = (w + 0.5f) * 0.25f - 0.5f;
    float fxf = floorf(sx);
    float fx = sx - fxf;
    int ix = (int)fxf;
    int x0 = min(max(ix, 0), 13), x1 = min(max(ix + 1, 0), 13);
    bh8 o;
#pragma unroll
    for (int j = 0; j < 8; ++j) {
      const float* s0 = sv + (g * 8 + j) * 15;
      const float* s1 = s0 + 64 * 15;
      float p00 = s0[x0] + (x0 > 0 ? s0[x0 - 1] : 0.f) + (x0 < 13 ? s0[x0 + 1] : 0.f);
      float p01 = s0[x1] + (x1 > 0 ? s0[x1 - 1] : 0.f) + (x1 < 13 ? s0[x1 + 1] : 0.f);
      float p10 = s1[x0] + (x0 > 0 ? s1[x0 - 1] : 0.f) + (x0 < 13 ? s1[x0 + 1] : 0.f);
      float p11 = s1[x1] + (x1 > 0 ? s1[x1 - 1] : 0.f) + (x1 < 13 ? s1[x1 + 1] : 0.f);
      float top = p00 + fx * (p01 - p00);
      float bot = p10 + fx * (p11 - p10);
      o[j] = f2bf((top + fy * (bot - top)) * (1.0f / 9.0f));
    }
    size_t pid = (size_t)b * HW_ + h * 56 + w;
    *(bh8*)(desc + pid * KD_ + C0_ + C1_ + c0 + g * 8) = o;
  }
}

// ---------------- |c_j|^2 from bf16-rounded C ----------------
__global__ void cent2_kernel(const float* __restrict__ C, float* __restrict__ c2) {
  int j = blockIdx.x * blockDim.x + threadIdx.x;
  if (j >= NC_) return;
  float s = 0.f;
  for (int d = 0; d < DOUT_; ++d) {
    float v = bf2f(f2bf(C[(size_t)d * NC_ + j]));
    s = fmaf(v, v, s);
  }
  c2[j] = s;
}

// ---------------- pack C (K=448 x N=3136) into B-frag layout ----------------
__global__ void cpack_kernel(const float* __restrict__ C, short* __restrict__ Cpk) {
  int idx = blockIdx.x * 256 + threadIdx.x;       // NCHD_*KCD_*64 = 175616 exact
  int ln = idx & 63;
  int kc = (idx >> 6) % KCD_;
  int nc = idx / (KCD_ * 64);
  int n  = nc * 16 + (ln & 15);
  int k0 = kc * 32 + ((ln >> 4) << 3);
  bh8 o;
#pragma unroll
  for (int j = 0; j < 8; ++j) o[j] = f2bf(C[(size_t)(k0 + j) * NC_ + n]);
  *(bh8*)(Cpk + (size_t)idx * 8) = o;
}

// ---------------- pack W^T (K=1792 x N=448) into B-frag layout ----------------
__global__ void wpack_kernel(const float* __restrict__ W, short* __restrict__ Wpk) {
  int idx = blockIdx.x * 256 + threadIdx.x;       // NCHP_*KCP_*64 = 100352 exact
  int ln = idx & 63;
  int kc = (idx >> 6) % KCP_;
  int nc = idx / (KCP_ * 64);
  int n  = nc * 16 + (ln & 15);
  int k0 = kc * 32 + ((ln >> 4) << 3);
  bh8 o;
#pragma unroll
  for (int j = 0; j < 8; ++j) o[j] = f2bf(W[(size_t)n * DIN_ + k0 + j]);
  *(bh8*)(Wpk + (size_t)idx * 8) = o;
}

// ======== phi: A-frags direct from desc; bias+coords fused; in-place phipack ========
__global__ __launch_bounds__(256) void phi_mfma(
    const short* __restrict__ desc, const short* __restrict__ Wpk,
    const float* __restrict__ cw, const float* __restrict__ cb,
    short* __restrict__ phip /* aliases desc */) {
  __shared__ __align__(16) float Dt[16 * DTS_];   // 28.9 KB
  const int wv = threadIdx.x >> 6, ln = threadIdx.x & 63;
  const int pix0 = blockIdx.x * 32;
  const short* aptr = desc + ((size_t)(pix0 + (ln & 15))) * KD_ + ((ln >> 4) << 3);

  f32x4 acc[2][7];
#pragma unroll
  for (int rc = 0; rc < 2; ++rc)
#pragma unroll
    for (int i = 0; i < 7; ++i) acc[rc][i] = (f32x4){0.f, 0.f, 0.f, 0.f};

  const short* bbase = Wpk + (size_t)(wv * 7) * (KCP_ * 512) + ln * 8;
  for (int kc = 0; kc < KCP_; ++kc) {
    bh8 a0 = *(const bh8*)(aptr + kc * 32);
    bh8 a1 = *(const bh8*)(aptr + 16 * KD_ + kc * 32);
    const short* bp = bbase + kc * 512;
#pragma unroll
    for (int i = 0; i < 7; ++i) {
      bh8 bfr = *(const bh8*)(bp + (size_t)i * (KCP_ * 512));
      acc[0][i] = __builtin_amdgcn_mfma_f32_16x16x32_bf16(a0, bfr, acc[0][i], 0, 0, 0);
      acc[1][i] = __builtin_amdgcn_mfma_f32_16x16x32_bf16(a1, bfr, acc[1][i], 0, 0, 0);
    }
  }

  for (int rc = 0; rc < 2; ++rc) {
    __syncthreads();   // rc=0: all desc reads done; rc=1: all rc=0 repack reads done
#pragma unroll
    for (int i = 0; i < 7; ++i) {
      int col = (wv * 7 + i) * 16 + (ln & 15);
      float bias = cb[col];
      float wx = cw[(size_t)col * DIN_ + 1792];
      float wy = cw[(size_t)col * DIN_ + 1793];
#pragma unroll
      for (int r = 0; r < 4; ++r) {
        int row = ((ln >> 4) << 2) + r;
        int pid = pix0 + rc * 16 + row;
        int hw = pid % HW_;
        int hh = hw / 56, ww = hw % 56;
        float xx = (float)hh * (2.0f / 55.0f) - 1.0f;
        float yy = (float)ww * (2.0f / 55.0f) - 1.0f;
        Dt[row * DTS_ + col] = acc[rc][i][r] + bias + wx * xx + wy * yy;
      }
    }
    __syncthreads();
    short* op = phip + (size_t)(blockIdx.x * 2 + rc) * PCH_;
    for (int item = threadIdx.x; item < KCD_ * 64; item += 256) {
      int kc = item >> 6, lp = item & 63;
      int m = lp & 15, k0 = kc * 32 + ((lp >> 4) << 3);
      bh8 o;
#pragma unroll
      for (int j = 0; j < 8; ++j) o[j] = f2bf(Dt[m * DTS_ + k0 + j]);
      *(bh8*)(op + (size_t)item * 8) = o;
    }
  }
}

// ---------------- dist: MFMA vs Cpack + streaming top-3 + softmin ----------------
__device__ __forceinline__ void insert3(float& t0, float& t1, float& t2, float v) {
  if (v < t2) {
    if (v < t1) {
      t2 = t1;
      if (v < t0) { t1 = t0; t0 = v; } else t1 = v;
    } else t2 = v;
  }
}
__device__ __forceinline__ void merge3(float& a0, float& a1, float& a2,
                                       float b0, float b1, float b2) {
  float lo0 = fminf(a0, b0), hi0 = fmaxf(a0, b0);
  float lo1 = fminf(a1, b1), hi1 = fmaxf(a1, b1);
  float lo2 = fminf(a2, b2);
  a0 = lo0;
  a1 = fminf(hi0, lo1);
  a2 = fminf(fmaxf(hi0, lo1), fminf(hi1, lo2));
}

__global__ __launch_bounds__(256) void dist_mfma(
    const short* __restrict__ phip, const short* __restrict__ Cpk,
    const float* __restrict__ c2g, float* __restrict__ out) {
  const int wv = threadIdx.x >> 6, ln = threadIdx.x & 63;

  bh8 A[2][KCD_];
#pragma unroll
  for (int rc = 0; rc < 2; ++rc) {
    const short* ap = phip + (size_t)(blockIdx.x * 2 + rc) * PCH_ + ln * 8;
#pragma unroll
    for (int kc = 0; kc < KCD_; ++kc) A[rc][kc] = *(const bh8*)(ap + kc * 512);
  }

  float f2r[2][4];
#pragma unroll
  for (int rc = 0; rc < 2; ++rc) {
    float sum = 0.f;
#pragma unroll
    for (int kc = 0; kc < KCD_; ++kc)
#pragma unroll
      for (int j = 0; j < 8; ++j) { float v = bf2f(A[rc][kc][j]); sum = fmaf(v, v, sum); }
    sum += __shfl_xor(sum, 16, 64);
    sum += __shfl_xor(sum, 32, 64);
#pragma unroll
    for (int r = 0; r < 4; ++r) f2r[rc][r] = __shfl(sum, ((ln >> 4) << 2) + r, 64);
  }

  float t3[2][4][3];
#pragma unroll
  for (int rc = 0; rc < 2; ++rc)
#pragma unroll
    for (int r = 0; r < 4; ++r) { t3[rc][r][0] = 1e30f; t3[rc][r][1] = 1e30f; t3[rc][r][2] = 1e30f; }

  for (int i = 0; i < NCHD_ / 4; ++i) {
    int nc = i * 4 + wv;
    f32x4 acc0 = {0.f, 0.f, 0.f, 0.f}, acc1 = {0.f, 0.f, 0.f, 0.f};
    const short* bp = Cpk + (size_t)nc * KCD_ * 512 + ln * 8;
#pragma unroll
    for (int kc = 0; kc < KCD_; ++kc) {
      bh8 b = *(const bh8*)(bp + kc * 512);
      acc0 = __builtin_amdgcn_mfma_f32_16x16x32_bf16(A[0][kc], b, acc0, 0, 0, 0);
      acc1 = __builtin_amdgcn_mfma_f32_16x16x32_bf16(A[1][kc], b, acc1, 0, 0, 0);
    }
    float c2v = c2g[nc * 16 + (ln & 15)];
#pragma unroll
    for (int r = 0; r < 4; ++r) {
      insert3(t3[0][r][0], t3[0][r][1], t3[0][r][2], f2r[0][r] + c2v - 2.0f * acc0[r]);
      insert3(t3[1][r][0], t3[1][r][1], t3[1][r][2], f2r[1][r] + c2v - 2.0f * acc1[r]);
    }
  }

#pragma unroll
  for (int m = 1; m <= 8; m <<= 1) {
#pragma unroll
    for (int rc = 0; rc < 2; ++rc)
#pragma unroll
      for (int r = 0; r < 4; ++r) {
        float b0 = __shfl_xor(t3[rc][r][0], m, 64);
        float b1 = __shfl_xor(t3[rc][r][1], m, 64);
        float b2 = __shfl_xor(t3[rc][r][2], m, 64);
        merge3(t3[rc][r][0], t3[rc][r][1], t3[rc][r][2], b0, b1, b2);
      }
  }

  __shared__ float mb[4][32][3];
  if ((ln & 15) == 0) {
#pragma unroll
    for (int rc = 0; rc < 2; ++rc)
#pragma unroll
      for (int r = 0; r < 4; ++r) {
        int row = rc * 16 + ((ln >> 4) << 2) + r;
        mb[wv][row][0] = t3[rc][r][0];
        mb[wv][row][1] = t3[rc][r][1];
        mb[wv][row][2] = t3[rc][r][2];
      }
  }
  __syncthreads();
  if (threadIdx.x < 32) {
    int row = threadIdx.x;
    float a0 = mb[0][row][0], a1 = mb[0][row][1], a2 = mb[0][row][2];
#pragma unroll
    for (int w2 = 1; w2 < 4; ++w2) merge3(a0, a1, a2, mb[w2][row][0], mb[w2][row][1], mb[w2][row][2]);
    float d0 = sqrtf(fmaxf(a0, 0.f));
    float d1 = sqrtf(fmaxf(a1, 0.f));
    float d2 = sqrtf(fmaxf(a2, 0.f));
    float s0 = 1.0f / (1.0f + expf(d0 - d1) + expf(d0 - d2));
    out[blockIdx.x * 32 + row] = s0 * d0;
  }
}

// ---------------- launch ----------------
extern "C" void kernel_launch(void* const* d_in, const int* in_sizes, int n_in,
                              void* d_out, int out_size, void* d_ws, size_t ws_size,
                              hipStream_t stream) {
  const float* p0 = (const float*)d_in[0];
  const float* p1 = (const float*)d_in[1];
  const float* p2 = (const float*)d_in[2];
  const float* cw = (const float*)d_in[3];
  const float* cb = (const float*)d_in[4];
  const float* C  = (const float*)d_in[5];
  float* out = (float*)d_out;

  // workspace (shorts): desc 44,957,696 + Cpk 1,404,928 + Wpk 802,816 (+c2) ~94.3 MB
  short* desc = (short*)d_ws;
  short* Cpk  = desc + (size_t)25088 * KD_;
  short* Wpk  = Cpk + (size_t)NCHD_ * KCD_ * 512;
  float* c2   = (float*)(Wpk + (size_t)NCHP_ * KCP_ * 512);

  desc0_kernel<<<dim3(4, 56, 8),  256, 0, stream>>>(p0, desc);
  desc1_kernel<<<dim3(8, 56, 8),  256, 0, stream>>>(p1, desc);
  desc2_kernel<<<dim3(16, 56, 8), 256, 0, stream>>>(p2, desc);
  cent2_kernel<<<(NC_ + 255) / 256, 256, 0, stream>>>(C, c2);
  cpack_kernel<<<NCHD_ * KCD_ * 64 / 256, 256, 0, stream>>>(C, Cpk);
  wpack_kernel<<<NCHP_ * KCP_ * 64 / 256, 256, 0, stream>>>(cw, Wpk);
  phi_mfma<<<25088 / 32, 256, 0, stream>>>(desc, Wpk, cw, cb, desc);
  dist_mfma<<<25088 / 32, 256, 0, stream>>>(desc, Cpk, c2, out);
}

// Round 4
// 738.367 us; speedup vs baseline: 5.3041x; 1.1509x over previous
//
#include <hip/hip_runtime.h>
#include <math.h>

// ---------------- problem constants ----------------
#define B_    8
#define H_    56
#define W_    56
#define HW_   3136
#define C0_   256
#define C1_   512
#define C2_   1024
#define DIN_  1794      // raw conv_w K (includes 2 coord cols, folded into epilogue)
#define KD_   1792      // descriptor K (GEMM K), 56 chunks of 32
#define KCP_  56        // phi K-chunks
#define DOUT_ 448
#define NCHP_ 28        // phi N-chunks (448/16)
#define NC_   3136      // centers
#define NCHD_ 196       // dist N-chunks (3136/16)
#define KCD_  14        // dist K-chunks (448/32)
#define DTS_  452       // LDS D-tile row stride (floats)
#define PCH_  28672     // phip chunk stride in shorts (= 16 pixels * 1792, in-place alias)

typedef __attribute__((ext_vector_type(8))) short bh8;
typedef __attribute__((ext_vector_type(4))) float f32x4;

__device__ __forceinline__ short f2bf(float f) {
  union { float f; unsigned u; } v; v.f = f;
  unsigned r = v.u + 0x7fffu + ((v.u >> 16) & 1u);
  return (short)(r >> 16);
}
__device__ __forceinline__ float bf2f(short s) {
  union { unsigned u; float f; } v; v.u = ((unsigned)(unsigned short)s) << 16;
  return v.f;
}

// ======== desc0: pool(p0) -> desc[:, 0:256], transposed, bf16 ========
__global__ __launch_bounds__(256) void desc0_kernel(const float* __restrict__ p0,
                                                    short* __restrict__ desc) {
  __shared__ float sv[64 * 57];
  const int c0 = blockIdx.x * 64, h = blockIdx.y, b = blockIdx.z;
  for (int item = threadIdx.x; item < 64 * 56; item += 256) {
    int x = item % 56, c = item / 56;
    const float* src = p0 + (((size_t)(b * C0_ + c0 + c)) * 56 + h) * 56 + x;
    float s = src[0];
    if (h > 0)  s += src[-56];
    if (h < 55) s += src[56];
    sv[c * 57 + x] = s;
  }
  __syncthreads();
  for (int item = threadIdx.x; item < 56 * 8; item += 256) {
    int g = item & 7, w = item >> 3;
    bh8 o;
#pragma unroll
    for (int j = 0; j < 8; ++j) {
      const float* s0 = sv + (g * 8 + j) * 57;
      float v = s0[w];
      if (w > 0)  v += s0[w - 1];
      if (w < 55) v += s0[w + 1];
      o[j] = f2bf(v * (1.0f / 9.0f));
    }
    size_t pid = (size_t)b * HW_ + h * 56 + w;
    *(bh8*)(desc + pid * KD_ + c0 + g * 8) = o;
  }
}

// ======== desc1: pool(p1)+bilinear x2 -> desc[:, 256:768] ========
__global__ __launch_bounds__(256) void desc1_kernel(const float* __restrict__ p1,
                                                    short* __restrict__ desc) {
  __shared__ float sv[2 * 64 * 29];
  const int c0 = blockIdx.x * 64, h = blockIdx.y, b = blockIdx.z;
  float sy = (h + 0.5f) * 0.5f - 0.5f;
  float fyf = floorf(sy);
  float fy = sy - fyf;
  int iy = (int)fyf;
  int pya = min(max(iy, 0), 27), pyb = min(max(iy + 1, 0), 27);
  for (int item = threadIdx.x; item < 64 * 2 * 28; item += 256) {
    int x = item % 28;
    int pr = (item / 28) & 1;
    int c = item / 56;
    int r = pr ? pyb : pya;
    const float* src = p1 + (((size_t)(b * C1_ + c0 + c)) * 28 + r) * 28 + x;
    float s = src[0];
    if (r > 0)  s += src[-28];
    if (r < 27) s += src[28];
    sv[pr * (64 * 29) + c * 29 + x] = s;
  }
  __syncthreads();
  for (int item = threadIdx.x; item < 56 * 8; item += 256) {
    int g = item & 7, w = item >> 3;
    float sx = (w + 0.5f) * 0.5f - 0.5f;
    float fxf = floorf(sx);
    float fx = sx - fxf;
    int ix = (int)fxf;
    int x0 = min(max(ix, 0), 27), x1 = min(max(ix + 1, 0), 27);
    bh8 o;
#pragma unroll
    for (int j = 0; j < 8; ++j) {
      const float* s0 = sv + (g * 8 + j) * 29;
      const float* s1 = s0 + 64 * 29;
      float p00 = s0[x0] + (x0 > 0 ? s0[x0 - 1] : 0.f) + (x0 < 27 ? s0[x0 + 1] : 0.f);
      float p01 = s0[x1] + (x1 > 0 ? s0[x1 - 1] : 0.f) + (x1 < 27 ? s0[x1 + 1] : 0.f);
      float p10 = s1[x0] + (x0 > 0 ? s1[x0 - 1] : 0.f) + (x0 < 27 ? s1[x0 + 1] : 0.f);
      float p11 = s1[x1] + (x1 > 0 ? s1[x1 - 1] : 0.f) + (x1 < 27 ? s1[x1 + 1] : 0.f);
      float top = p00 + fx * (p01 - p00);
      float bot = p10 + fx * (p11 - p10);
      o[j] = f2bf((top + fy * (bot - top)) * (1.0f / 9.0f));
    }
    size_t pid = (size_t)b * HW_ + h * 56 + w;
    *(bh8*)(desc + pid * KD_ + C0_ + c0 + g * 8) = o;
  }
}

// ======== desc2: pool(p2)+bilinear x4 -> desc[:, 768:1792] ========
__global__ __launch_bounds__(256) void desc2_kernel(const float* __restrict__ p2,
                                                    short* __restrict__ desc) {
  __shared__ float sv[2 * 64 * 15];
  const int c0 = blockIdx.x * 64, h = blockIdx.y, b = blockIdx.z;
  float sy = (h + 0.5f) * 0.25f - 0.5f;
  float fyf = floorf(sy);
  float fy = sy - fyf;
  int iy = (int)fyf;
  int pya = min(max(iy, 0), 13), pyb = min(max(iy + 1, 0), 13);
  for (int item = threadIdx.x; item < 64 * 2 * 14; item += 256) {
    int x = item % 14;
    int pr = (item / 14) & 1;
    int c = item / 28;
    int r = pr ? pyb : pya;
    const float* src = p2 + (((size_t)(b * C2_ + c0 + c)) * 14 + r) * 14 + x;
    float s = src[0];
    if (r > 0)  s += src[-14];
    if (r < 13) s += src[14];
    sv[pr * (64 * 15) + c * 15 + x] = s;
  }
  __syncthreads();
  for (int item = threadIdx.x; item < 56 * 8; item += 256) {
    int g = item & 7, w = item >> 3;
    float sx = (w + 0.5f) * 0.25f - 0.5f;
    float fxf = floorf(sx);
    float fx = sx - fxf;
    int ix = (int)fxf;
    int x0 = min(max(ix, 0), 13), x1 = min(max(ix + 1, 0), 13);
    bh8 o;
#pragma unroll
    for (int j = 0; j < 8; ++j) {
      const float* s0 = sv + (g * 8 + j) * 15;
      const float* s1 = s0 + 64 * 15;
      float p00 = s0[x0] + (x0 > 0 ? s0[x0 - 1] : 0.f) + (x0 < 13 ? s0[x0 + 1] : 0.f);
      float p01 = s0[x1] + (x1 > 0 ? s0[x1 - 1] : 0.f) + (x1 < 13 ? s0[x1 + 1] : 0.f);
      float p10 = s1[x0] + (x0 > 0 ? s1[x0 - 1] : 0.f) + (x0 < 13 ? s1[x0 + 1] : 0.f);
      float p11 = s1[x1] + (x1 > 0 ? s1[x1 - 1] : 0.f) + (x1 < 13 ? s1[x1 + 1] : 0.f);
      float top = p00 + fx * (p01 - p00);
      float bot = p10 + fx * (p11 - p10);
      o[j] = f2bf((top + fy * (bot - top)) * (1.0f / 9.0f));
    }
    size_t pid = (size_t)b * HW_ + h * 56 + w;
    *(bh8*)(desc + pid * KD_ + C0_ + C1_ + c0 + g * 8) = o;
  }
}

// ---------------- |c_j|^2 from bf16-rounded C ----------------
__global__ void cent2_kernel(const float* __restrict__ C, float* __restrict__ c2) {
  int j = blockIdx.x * blockDim.x + threadIdx.x;
  if (j >= NC_) return;
  float s = 0.f;
  for (int d = 0; d < DOUT_; ++d) {
    float v = bf2f(f2bf(C[(size_t)d * NC_ + j]));
    s = fmaf(v, v, s);
  }
  c2[j] = s;
}

// ---------------- pack C (K=448 x N=3136) into B-frag layout ----------------
__global__ void cpack_kernel(const float* __restrict__ C, short* __restrict__ Cpk) {
  int idx = blockIdx.x * 256 + threadIdx.x;       // NCHD_*KCD_*64 = 175616 exact
  int ln = idx & 63;
  int kc = (idx >> 6) % KCD_;
  int nc = idx / (KCD_ * 64);
  int n  = nc * 16 + (ln & 15);
  int k0 = kc * 32 + ((ln >> 4) << 3);
  bh8 o;
#pragma unroll
  for (int j = 0; j < 8; ++j) o[j] = f2bf(C[(size_t)(k0 + j) * NC_ + n]);
  *(bh8*)(Cpk + (size_t)idx * 8) = o;
}

// ---------------- pack W^T (K=1792 x N=448) into B-frag layout ----------------
__global__ void wpack_kernel(const float* __restrict__ W, short* __restrict__ Wpk) {
  int idx = blockIdx.x * 256 + threadIdx.x;       // NCHP_*KCP_*64 = 100352 exact
  int ln = idx & 63;
  int kc = (idx >> 6) % KCP_;
  int nc = idx / (KCP_ * 64);
  int n  = nc * 16 + (ln & 15);
  int k0 = kc * 32 + ((ln >> 4) << 3);
  bh8 o;
#pragma unroll
  for (int j = 0; j < 8; ++j) o[j] = f2bf(W[(size_t)n * DIN_ + k0 + j]);
  *(bh8*)(Wpk + (size_t)idx * 8) = o;
}

// ======== phi: A-frags direct from desc; bias+coords fused; in-place phipack ========
__global__ __launch_bounds__(256) void phi_mfma(
    const short* __restrict__ desc, const short* __restrict__ Wpk,
    const float* __restrict__ cw, const float* __restrict__ cb,
    short* __restrict__ phip /* aliases desc */) {
  __shared__ __align__(16) float Dt[16 * DTS_];   // 28.9 KB
  const int wv = threadIdx.x >> 6, ln = threadIdx.x & 63;
  const int pix0 = blockIdx.x * 32;
  const short* aptr = desc + ((size_t)(pix0 + (ln & 15))) * KD_ + ((ln >> 4) << 3);

  f32x4 acc[2][7];
#pragma unroll
  for (int rc = 0; rc < 2; ++rc)
#pragma unroll
    for (int i = 0; i < 7; ++i) acc[rc][i] = (f32x4){0.f, 0.f, 0.f, 0.f};

  const short* bbase = Wpk + (size_t)(wv * 7) * (KCP_ * 512) + ln * 8;
  for (int kc = 0; kc < KCP_; ++kc) {
    bh8 a0 = *(const bh8*)(aptr + kc * 32);
    bh8 a1 = *(const bh8*)(aptr + 16 * KD_ + kc * 32);
    const short* bp = bbase + kc * 512;
#pragma unroll
    for (int i = 0; i < 7; ++i) {
      bh8 bfr = *(const bh8*)(bp + (size_t)i * (KCP_ * 512));
      acc[0][i] = __builtin_amdgcn_mfma_f32_16x16x32_bf16(a0, bfr, acc[0][i], 0, 0, 0);
      acc[1][i] = __builtin_amdgcn_mfma_f32_16x16x32_bf16(a1, bfr, acc[1][i], 0, 0, 0);
    }
  }

  for (int rc = 0; rc < 2; ++rc) {
    __syncthreads();   // rc=0: all desc reads done; rc=1: all rc=0 repack reads done
#pragma unroll
    for (int i = 0; i < 7; ++i) {
      int col = (wv * 7 + i) * 16 + (ln & 15);
      float bias = cb[col];
      float wx = cw[(size_t)col * DIN_ + 1792];
      float wy = cw[(size_t)col * DIN_ + 1793];
#pragma unroll
      for (int r = 0; r < 4; ++r) {
        int row = ((ln >> 4) << 2) + r;
        int pid = pix0 + rc * 16 + row;
        int hw = pid % HW_;
        int hh = hw / 56, ww = hw % 56;
        float xx = (float)hh * (2.0f / 55.0f) - 1.0f;
        float yy = (float)ww * (2.0f / 55.0f) - 1.0f;
        Dt[row * DTS_ + col] = acc[rc][i][r] + bias + wx * xx + wy * yy;
      }
    }
    __syncthreads();
    short* op = phip + (size_t)(blockIdx.x * 2 + rc) * PCH_;
    for (int item = threadIdx.x; item < KCD_ * 64; item += 256) {
      int kc = item >> 6, lp = item & 63;
      int m = lp & 15, k0 = kc * 32 + ((lp >> 4) << 3);
      bh8 o;
#pragma unroll
      for (int j = 0; j < 8; ++j) o[j] = f2bf(Dt[m * DTS_ + k0 + j]);
      *(bh8*)(op + (size_t)item * 8) = o;
    }
  }
}

// ======== dist v2: wave owns 16 pixels, streams all 196 N-chunks ========
// A-frags = 14 bh8 = 56 VGPR (no spill); no LDS, no syncthreads;
// __launch_bounds__(256,2) caps allocator at 256 VGPR so it never spills.
__device__ __forceinline__ void insert3(float& t0, float& t1, float& t2, float v) {
  if (v < t2) {
    if (v < t1) {
      t2 = t1;
      if (v < t0) { t1 = t0; t0 = v; } else t1 = v;
    } else t2 = v;
  }
}
__device__ __forceinline__ void merge3(float& a0, float& a1, float& a2,
                                       float b0, float b1, float b2) {
  float lo0 = fminf(a0, b0), hi0 = fmaxf(a0, b0);
  float lo1 = fminf(a1, b1), hi1 = fmaxf(a1, b1);
  float lo2 = fminf(a2, b2);
  a0 = lo0;
  a1 = fminf(hi0, lo1);
  a2 = fminf(fmaxf(hi0, lo1), fminf(hi1, lo2));
}

__global__ __launch_bounds__(256, 2) void dist_mfma(
    const short* __restrict__ phip, const short* __restrict__ Cpk,
    const float* __restrict__ c2g, float* __restrict__ out) {
  const int wv = threadIdx.x >> 6, ln = threadIdx.x & 63;
  const int chunk = blockIdx.x * 4 + wv;   // 16-pixel chunk, 1568 total

  bh8 A[KCD_];
  const short* ap = phip + (size_t)chunk * PCH_ + ln * 8;
#pragma unroll
  for (int kc = 0; kc < KCD_; ++kc) A[kc] = *(const bh8*)(ap + kc * 512);

  // f2 per pixel row (self-consistent with bf16 MFMA dot)
  float sum = 0.f;
#pragma unroll
  for (int kc = 0; kc < KCD_; ++kc)
#pragma unroll
    for (int j = 0; j < 8; ++j) { float v = bf2f(A[kc][j]); sum = fmaf(v, v, sum); }
  sum += __shfl_xor(sum, 16, 64);
  sum += __shfl_xor(sum, 32, 64);
  float f2r[4];
#pragma unroll
  for (int r = 0; r < 4; ++r) f2r[r] = __shfl(sum, ((ln >> 4) << 2) + r, 64);

  float t3[4][3];
#pragma unroll
  for (int r = 0; r < 4; ++r) { t3[r][0] = 1e30f; t3[r][1] = 1e30f; t3[r][2] = 1e30f; }

  const short* bbase = Cpk + ln * 8;
  for (int i = 0; i < NCHD_ / 2; ++i) {
    int ncA = i * 2, ncB = i * 2 + 1;
    const short* bpA = bbase + (size_t)ncA * (KCD_ * 512);
    const short* bpB = bbase + (size_t)ncB * (KCD_ * 512);
    f32x4 accA = {0.f, 0.f, 0.f, 0.f}, accB = {0.f, 0.f, 0.f, 0.f};
#pragma unroll
    for (int kc = 0; kc < KCD_; ++kc) {
      bh8 bA = *(const bh8*)(bpA + kc * 512);
      bh8 bB = *(const bh8*)(bpB + kc * 512);
      accA = __builtin_amdgcn_mfma_f32_16x16x32_bf16(A[kc], bA, accA, 0, 0, 0);
      accB = __builtin_amdgcn_mfma_f32_16x16x32_bf16(A[kc], bB, accB, 0, 0, 0);
    }
    float c2A = c2g[ncA * 16 + (ln & 15)];
    float c2B = c2g[ncB * 16 + (ln & 15)];
#pragma unroll
    for (int r = 0; r < 4; ++r) {
      insert3(t3[r][0], t3[r][1], t3[r][2], f2r[r] + c2A - 2.0f * accA[r]);
      insert3(t3[r][0], t3[r][1], t3[r][2], f2r[r] + c2B - 2.0f * accB[r]);
    }
  }

  // merge the 16 lanes (same rows, different center columns)
#pragma unroll
  for (int m = 1; m <= 8; m <<= 1) {
#pragma unroll
    for (int r = 0; r < 4; ++r) {
      float b0 = __shfl_xor(t3[r][0], m, 64);
      float b1 = __shfl_xor(t3[r][1], m, 64);
      float b2 = __shfl_xor(t3[r][2], m, 64);
      merge3(t3[r][0], t3[r][1], t3[r][2], b0, b1, b2);
    }
  }

  if ((ln & 15) == 0) {
#pragma unroll
    for (int r = 0; r < 4; ++r) {
      float d0 = sqrtf(fmaxf(t3[r][0], 0.f));
      float d1 = sqrtf(fmaxf(t3[r][1], 0.f));
      float d2 = sqrtf(fmaxf(t3[r][2], 0.f));
      float s0 = 1.0f / (1.0f + expf(d0 - d1) + expf(d0 - d2));
      out[chunk * 16 + ((ln >> 4) << 2) + r] = s0 * d0;
    }
  }
}

// ---------------- launch ----------------
extern "C" void kernel_launch(void* const* d_in, const int* in_sizes, int n_in,
                              void* d_out, int out_size, void* d_ws, size_t ws_size,
                              hipStream_t stream) {
  const float* p0 = (const float*)d_in[0];
  const float* p1 = (const float*)d_in[1];
  const float* p2 = (const float*)d_in[2];
  const float* cw = (const float*)d_in[3];
  const float* cb = (const float*)d_in[4];
  const float* C  = (const float*)d_in[5];
  float* out = (float*)d_out;

  short* desc = (short*)d_ws;
  short* Cpk  = desc + (size_t)25088 * KD_;
  short* Wpk  = Cpk + (size_t)NCHD_ * KCD_ * 512;
  float* c2   = (float*)(Wpk + (size_t)NCHP_ * KCP_ * 512);

  desc0_kernel<<<dim3(4, 56, 8),  256, 0, stream>>>(p0, desc);
  desc1_kernel<<<dim3(8, 56, 8),  256, 0, stream>>>(p1, desc);
  desc2_kernel<<<dim3(16, 56, 8), 256, 0, stream>>>(p2, desc);
  cent2_kernel<<<(NC_ + 255) / 256, 256, 0, stream>>>(C, c2);
  cpack_kernel<<<NCHD_ * KCD_ * 64 / 256, 256, 0, stream>>>(C, Cpk);
  wpack_kernel<<<NCHP_ * KCP_ * 64 / 256, 256, 0, stream>>>(cw, Wpk);
  phi_mfma<<<25088 / 32, 256, 0, stream>>>(desc, Wpk, cw, cb, desc);
  dist_mfma<<<25088 / 64, 256, 0, stream>>>(desc, Cpk, c2, out);
}